// Round 2
// baseline (2921.069 us; speedup 1.0000x reference)
//
#include <hip/hip_runtime.h>

#define THRESH 0.1f

// ---------------------------------------------------------------------------
// Weight norm: w[row,:] = g[row] * v[row,:] / ||v[row,:]||   (one wave / row)
// ---------------------------------------------------------------------------
__global__ void wnorm_kernel(const float* __restrict__ v, const float* __restrict__ g,
                             float* __restrict__ w, int fanin) {
    int row = blockIdx.x;
    const float* vr = v + (size_t)row * fanin;
    float ss = 0.f;
    for (int i = threadIdx.x; i < fanin; i += 64) { float x = vr[i]; ss = fmaf(x, x, ss); }
    #pragma unroll
    for (int off = 32; off > 0; off >>= 1) ss += __shfl_down(ss, off);
    ss = __shfl(ss, 0);
    float scale = g[row] / sqrtf(ss);
    float* wr = w + (size_t)row * fanin;
    for (int i = threadIdx.x; i < fanin; i += 64) wr[i] = vr[i] * scale;
}

// ---------------------------------------------------------------------------
// Fused 3x3 SAME conv + IAF (integrate & fire, membrane-subtract) + 2x2 avgpool.
// One thread owns ONE conv pixel (one IAF state); the 4 lanes of a 2x2 quad
// are adjacent in the wave, pooled via exact __shfl_xor adds of 0/1 spikes.
// Per-pixel fmaf sequence over (cin,ky,kx) is identical to the round-1 kernel
// -> bitwise identical output (absmax margin is tight, don't touch ordering).
// in : (B*T, CIN, H, H), w : (COUT, CIN, 3, 3), out: (B*T, COUT, H/2, H/2)
// ---------------------------------------------------------------------------
template<int CIN, int H, int COUT>
__launch_bounds__(256)
__global__ void conv_iaf_pool(const float* __restrict__ in, const float* __restrict__ w,
                              float* __restrict__ out, int B, int T) {
    constexpr int Hp  = H / 2;
    constexpr int PP  = Hp * Hp;          // pooled pixels per (b, c)
    constexpr int TPC = PP * 4;           // threads per c_out
    constexpr int CPB = (TPC >= 256) ? 1 : (256 / TPC);  // c_outs per block
    __shared__ float lw[CPB * CIN * 9];

    const int m   = blockIdx.x * 256 + threadIdx.x;   // grid sized exactly
    const int q   = m & 3;                            // sub-pixel in 2x2 quad
    const int pix = (m >> 2) % PP;
    const int c   = ((m >> 2) / PP) % COUT;
    const int b   = (m >> 2) / PP / COUT;
    const int c0  = ((blockIdx.x * 256) / TPC) % COUT;

    for (int i = threadIdx.x; i < CPB * CIN * 9; i += 256)
        lw[i] = w[(size_t)c0 * CIN * 9 + i];
    __syncthreads();

    const float* wc = lw + (c - c0) * (CIN * 9);
    const int xp = pix % Hp, yp = pix / Hp;
    const int y = 2 * yp + (q >> 1), x = 2 * xp + (q & 1);

    float v = 0.f;                                    // membrane potential

    for (int t = 0; t < T; ++t) {
        const float* inb = in + (size_t)(b * T + t) * (CIN * H * H);
        float a = 0.f;
        for (int ci = 0; ci < CIN; ++ci) {
            const float* ib = inb + ci * (H * H);
            float p[9];
            #pragma unroll
            for (int r = 0; r < 3; ++r) {
                const int yy = y - 1 + r;
                const bool yok = ((unsigned)yy < (unsigned)H);
                #pragma unroll
                for (int cc = 0; cc < 3; ++cc) {
                    const int xx = x - 1 + cc;
                    p[r * 3 + cc] = (yok && ((unsigned)xx < (unsigned)H)) ? ib[yy * H + xx] : 0.f;
                }
            }
            const float* wk = wc + ci * 9;
            #pragma unroll
            for (int k = 0; k < 9; ++k) a = fmaf(p[k], wk[k], a);
        }
        v += a;
        float s = (v >= THRESH) ? 1.f : 0.f;
        v -= THRESH * s;
        float sum = s;                                 // exact 0/1 sums
        sum += __shfl_xor(sum, 1);
        sum += __shfl_xor(sum, 2);
        if (q == 0)
            out[((size_t)(b * T + t) * COUT + c) * PP + pix] = 0.25f * sum;
    }
}

// ---------------------------------------------------------------------------
// Linear: out (1600, 11) = h (1600, 1024) @ w^T (11, 1024)
// One block per row; 16 k-chunks x 16 j-slots of 64-long partials, LDS reduce.
// ---------------------------------------------------------------------------
__global__ void linear_kernel(const float* __restrict__ h, const float* __restrict__ w,
                              float* __restrict__ out) {
    __shared__ float hs[1024];
    __shared__ float part[16][17];
    const int n = blockIdx.x;
    for (int i = threadIdx.x; i < 1024; i += blockDim.x)
        hs[i] = h[(size_t)n * 1024 + i];
    __syncthreads();
    const int j = threadIdx.x & 15, ch = threadIdx.x >> 4;
    float acc = 0.f;
    if (j < 11) {
        const float* wr = w + (size_t)j * 1024 + ch * 64;
        const float* hh = hs + ch * 64;
        #pragma unroll 8
        for (int k = 0; k < 64; ++k) acc = fmaf(hh[k], wr[k], acc);
    }
    part[j][ch] = acc;
    __syncthreads();
    if (threadIdx.x < 11) {
        float s = 0.f;
        #pragma unroll
        for (int cc = 0; cc < 16; ++cc) s += part[threadIdx.x][cc];
        out[(size_t)n * 11 + threadIdx.x] = s;
    }
}

// ---------------------------------------------------------------------------
extern "C" void kernel_launch(void* const* d_in, const int* in_sizes, int n_in,
                              void* d_out, int out_size, void* d_ws, size_t ws_size,
                              hipStream_t stream) {
    const int B = 32, T = 50;

    const float* x   = (const float*)d_in[0];
    const float* c0v = (const float*)d_in[1];
    const float* c0g = (const float*)d_in[2];
    const float* c1v = (const float*)d_in[3];
    const float* c1g = (const float*)d_in[4];
    const float* c2v = (const float*)d_in[5];
    const float* c2g = (const float*)d_in[6];
    const float* c3v = (const float*)d_in[7];
    const float* c3g = (const float*)d_in[8];
    const float* lv  = (const float*)d_in[9];
    const float* lg  = (const float*)d_in[10];
    float* out = (float*)d_out;

    // Workspace layout (floats)
    float* ws = (float*)d_ws;
    float* w0 = ws;                    // 8*2*9     = 144
    float* w1 = w0 + 144;              // 16*8*9    = 1152
    float* w2 = w1 + 1152;             // 32*16*9   = 4608
    float* w3 = w2 + 4608;             // 64*32*9   = 18432
    float* wl = w3 + 18432;            // 11*1024   = 11264
    float* bufA = ws + 40960;                  // L0 out: 1600*8*32*32  = 13,107,200
    float* bufB = bufA + (size_t)13107200;     // L1 out: 1600*16*16*16 =  6,553,600
    // L2 out (3,276,800) reuses bufA; L3 out (1,638,400) reuses bufB.

    // Normalized weights
    wnorm_kernel<<<8,  64, 0, stream>>>(c0v, c0g, w0, 2 * 9);
    wnorm_kernel<<<16, 64, 0, stream>>>(c1v, c1g, w1, 8 * 9);
    wnorm_kernel<<<32, 64, 0, stream>>>(c2v, c2g, w2, 16 * 9);
    wnorm_kernel<<<64, 64, 0, stream>>>(c3v, c3g, w3, 32 * 9);
    wnorm_kernel<<<11, 64, 0, stream>>>(lv,  lg,  wl, 1024);

    // Grid = B*COUT*PP*4 / 256 blocks (one thread per conv pixel)
    conv_iaf_pool<2, 64, 8><<<4096, 256, 0, stream>>>(x, w0, bufA, B, T);     // L0
    conv_iaf_pool<8, 32, 16><<<2048, 256, 0, stream>>>(bufA, w1, bufB, B, T); // L1
    conv_iaf_pool<16, 16, 32><<<1024, 256, 0, stream>>>(bufB, w2, bufA, B, T);// L2
    conv_iaf_pool<32, 8, 64><<<512, 256, 0, stream>>>(bufA, w3, bufB, B, T);  // L3

    // Linear: (1600,1024) @ (11,1024)^T -> (1600,11)
    linear_kernel<<<B * T, 256, 0, stream>>>(bufB, wl, out);
}

// Round 3
// 1698.605 us; speedup vs baseline: 1.7197x; 1.7197x over previous
//
#include <hip/hip_runtime.h>

#define THRESH 0.1f

// ---------------------------------------------------------------------------
// Weight norm: w[row,:] = g[row] * v[row,:] / ||v[row,:]||   (one wave / row)
// (unchanged from round 1/2 — weight bits must stay identical)
// ---------------------------------------------------------------------------
__global__ void wnorm_kernel(const float* __restrict__ v, const float* __restrict__ g,
                             float* __restrict__ w, int fanin) {
    int row = blockIdx.x;
    const float* vr = v + (size_t)row * fanin;
    float ss = 0.f;
    for (int i = threadIdx.x; i < fanin; i += 64) { float x = vr[i]; ss = fmaf(x, x, ss); }
    #pragma unroll
    for (int off = 32; off > 0; off >>= 1) ss += __shfl_down(ss, off);
    ss = __shfl(ss, 0);
    float scale = g[row] / sqrtf(ss);
    float* wr = w + (size_t)row * fanin;
    for (int i = threadIdx.x; i < fanin; i += 64) wr[i] = vr[i] * scale;
}

// ---------------------------------------------------------------------------
// Fused conv3x3(SAME) + IAF + 2x2 avgpool, LDS-staged.
// Block = 256 threads = one b, a strip of conv rows, NCG c-groups as needed.
// Per t: stage input strip (with zero halo) to LDS, each thread computes ONE
// conv pixel for CG c_outs; pool via __shfl_xor over the 2x2 quad (lanes q=0..3).
// Weights: wave-uniform pointer (readfirstlane) -> scalar loads; or VGPR-resident
// when CG*CIN*9 small (L0). Per-(pixel,c) fmaf order is (ci,ky,kx) — identical
// floats & ordering to rounds 1/2 -> bitwise-identical spikes.
// ---------------------------------------------------------------------------
template<int CIN, int H, int COUT, int CG, int ST>
__launch_bounds__(256)
__global__ void conv_iaf_pool(const float* __restrict__ in, const float* __restrict__ w,
                              float* __restrict__ out, int B, int T) {
    constexpr int Hp  = H / 2;
    constexpr int PP  = Hp * Hp;
    constexpr int NCG = COUT / CG;
    constexpr int PRB = (64 / Hp < Hp) ? (64 / Hp) : Hp;   // pooled rows per block
    constexpr int RS  = 2 * PRB;                            // conv rows per block
    constexpr int SLAB = CIN * (RS + 2) * ST;
    __shared__ float slab[SLAB];

    const int tid = threadIdx.x;
    const int m   = blockIdx.x * 256 + tid;
    const int q   = m & 3;
    const int pix = (m >> 2) % PP;
    const int cgi = ((m >> 2) / PP) % NCG;
    const int b   = m / (4 * PP * NCG);
    const int c0  = __builtin_amdgcn_readfirstlane(cgi) * CG;   // wave-uniform
    const float* __restrict__ wu = w + (size_t)c0 * (CIN * 9);

    const int yp = pix / Hp, xp = pix % Hp;
    const int y  = 2 * yp + (q >> 1), x = 2 * xp + (q & 1);
    const int y0 = 2 * (((blockIdx.x * 64) % PP) / Hp);     // first conv row of strip

    // ---- staging offsets, computed once, reused for all T steps ----
    constexpr int E = CIN * (RS + 2) * (H + 2);
    constexpr int ITERS = (E + 255) / 256;
    int goff[ITERS], loff[ITERS];
    #pragma unroll
    for (int i = 0; i < ITERS; ++i) {
        const int idx = tid + i * 256;
        const int j  = idx % (H + 2);
        const int rr = (idx / (H + 2)) % (RS + 2);
        const int ci = idx / ((H + 2) * (RS + 2));
        const int gy = y0 - 1 + rr, gx = j - 1;
        const bool ok = (idx < E) && ((unsigned)gy < (unsigned)H) && ((unsigned)gx < (unsigned)H);
        goff[i] = ok ? (ci * (H * H) + gy * H + gx) : -1;
        loff[i] = (idx < E) ? (ci * ((RS + 2) * ST) + rr * ST + j) : -1;
    }

    // ---- weights resident in VGPRs when small enough (L0) ----
    constexpr bool WREG = (CG * CIN * 9) <= 80;
    float wreg[WREG ? (CG * CIN * 9) : 1];
    if constexpr (WREG) {
        #pragma unroll
        for (int i = 0; i < CG * CIN * 9; ++i) wreg[i] = wu[i];
    }

    const float* pbase = slab + (y - y0) * ST + x;   // patch base (row y-1 staged at y-y0)

    float v[CG];
    #pragma unroll
    for (int c = 0; c < CG; ++c) v[c] = 0.f;

    for (int t = 0; t < T; ++t) {
        const float* inb = in + (size_t)(b * T + t) * (CIN * H * H);
        __syncthreads();                             // protect LDS from prev-t readers
        #pragma unroll
        for (int i = 0; i < ITERS; ++i) {
            if (loff[i] >= 0)
                slab[loff[i]] = (goff[i] >= 0) ? inb[goff[i]] : 0.f;
        }
        __syncthreads();

        float acc[CG];
        #pragma unroll
        for (int c = 0; c < CG; ++c) acc[c] = 0.f;

        constexpr int CIU = (CIN < 8) ? CIN : 8;
        for (int cio = 0; cio < CIN; cio += CIU) {
            #pragma unroll
            for (int cii = 0; cii < CIU; ++cii) {
                const int ci = cio + cii;
                const float* pb = pbase + ci * ((RS + 2) * ST);
                float p[9];
                #pragma unroll
                for (int r = 0; r < 3; ++r)
                    #pragma unroll
                    for (int cc = 0; cc < 3; ++cc)
                        p[r * 3 + cc] = pb[r * ST + cc];
                #pragma unroll
                for (int c = 0; c < CG; ++c) {
                    #pragma unroll
                    for (int k = 0; k < 9; ++k) {
                        const float wv = WREG ? wreg[(c * CIN + ci) * 9 + k]
                                              : wu[(size_t)c * (CIN * 9) + ci * 9 + k];
                        acc[c] = fmaf(p[k], wv, acc[c]);
                    }
                }
            }
        }

        #pragma unroll
        for (int c = 0; c < CG; ++c) {
            v[c] += acc[c];
            float s = (v[c] >= THRESH) ? 1.f : 0.f;
            v[c] -= THRESH * s;
            float sum = s;                           // exact 0/1 sums
            sum += __shfl_xor(sum, 1);
            sum += __shfl_xor(sum, 2);
            if (q == 0)
                out[((size_t)(b * T + t) * COUT + (c0 + c)) * PP + pix] = 0.25f * sum;
        }
    }
}

// ---------------------------------------------------------------------------
// Linear: out (1600, 11) = h (1600, 1024) @ w^T (11, 1024)
// ---------------------------------------------------------------------------
__global__ void linear_kernel(const float* __restrict__ h, const float* __restrict__ w,
                              float* __restrict__ out) {
    __shared__ float hs[1024];
    __shared__ float part[16][17];
    const int n = blockIdx.x;
    for (int i = threadIdx.x; i < 1024; i += blockDim.x)
        hs[i] = h[(size_t)n * 1024 + i];
    __syncthreads();
    const int j = threadIdx.x & 15, ch = threadIdx.x >> 4;
    float acc = 0.f;
    if (j < 11) {
        const float* wr = w + (size_t)j * 1024 + ch * 64;
        const float* hh = hs + ch * 64;
        #pragma unroll 8
        for (int k = 0; k < 64; ++k) acc = fmaf(hh[k], wr[k], acc);
    }
    part[j][ch] = acc;
    __syncthreads();
    if (threadIdx.x < 11) {
        float s = 0.f;
        #pragma unroll
        for (int cc = 0; cc < 16; ++cc) s += part[threadIdx.x][cc];
        out[(size_t)n * 11 + threadIdx.x] = s;
    }
}

// ---------------------------------------------------------------------------
extern "C" void kernel_launch(void* const* d_in, const int* in_sizes, int n_in,
                              void* d_out, int out_size, void* d_ws, size_t ws_size,
                              hipStream_t stream) {
    const int B = 32, T = 50;

    const float* x   = (const float*)d_in[0];
    const float* c0v = (const float*)d_in[1];
    const float* c0g = (const float*)d_in[2];
    const float* c1v = (const float*)d_in[3];
    const float* c1g = (const float*)d_in[4];
    const float* c2v = (const float*)d_in[5];
    const float* c2g = (const float*)d_in[6];
    const float* c3v = (const float*)d_in[7];
    const float* c3g = (const float*)d_in[8];
    const float* lv  = (const float*)d_in[9];
    const float* lg  = (const float*)d_in[10];
    float* out = (float*)d_out;

    // Workspace layout (floats)
    float* ws = (float*)d_ws;
    float* w0 = ws;                    // 8*2*9     = 144
    float* w1 = w0 + 144;              // 16*8*9    = 1152
    float* w2 = w1 + 1152;             // 32*16*9   = 4608
    float* w3 = w2 + 4608;             // 64*32*9   = 18432
    float* wl = w3 + 18432;            // 11*1024   = 11264
    float* bufA = ws + 40960;                  // L0 out: 1600*8*32*32  = 13,107,200
    float* bufB = bufA + (size_t)13107200;     // L1 out: 1600*16*16*16 =  6,553,600
    // L2 out (3,276,800) reuses bufA; L3 out (1,638,400) reuses bufB.

    wnorm_kernel<<<8,  64, 0, stream>>>(c0v, c0g, w0, 2 * 9);
    wnorm_kernel<<<16, 64, 0, stream>>>(c1v, c1g, w1, 8 * 9);
    wnorm_kernel<<<32, 64, 0, stream>>>(c2v, c2g, w2, 16 * 9);
    wnorm_kernel<<<64, 64, 0, stream>>>(c3v, c3g, w3, 32 * 9);
    wnorm_kernel<<<11, 64, 0, stream>>>(lv,  lg,  wl, 1024);

    // <CIN, H, COUT, CG, ST>; threads = B * (COUT/CG) * PP * 4
    conv_iaf_pool<2, 64, 8, 4, 66><<<1024, 256, 0, stream>>>(x, w0, bufA, B, T);     // L0
    conv_iaf_pool<8, 32, 16, 2, 34><<<1024, 256, 0, stream>>>(bufA, w1, bufB, B, T); // L1
    conv_iaf_pool<16, 16, 32, 2, 24><<<512, 256, 0, stream>>>(bufB, w2, bufA, B, T); // L2
    conv_iaf_pool<32, 8, 64, 1, 12><<<512, 256, 0, stream>>>(bufA, w3, bufB, B, T);  // L3

    linear_kernel<<<B * T, 256, 0, stream>>>(bufB, wl, out);
}

// Round 4
// 831.026 us; speedup vs baseline: 3.5150x; 2.0440x over previous
//
#include <hip/hip_runtime.h>

#define THRESH 0.1f

// ---------------------------------------------------------------------------
// Weight norm: w[row,:] = g[row] * v[row,:] / ||v[row,:]||   (one wave / row)
// (unchanged — weight bits must stay identical across rounds)
// ---------------------------------------------------------------------------
__global__ void wnorm_kernel(const float* __restrict__ v, const float* __restrict__ g,
                             float* __restrict__ w, int fanin) {
    int row = blockIdx.x;
    const float* vr = v + (size_t)row * fanin;
    float ss = 0.f;
    for (int i = threadIdx.x; i < fanin; i += 64) { float x = vr[i]; ss = fmaf(x, x, ss); }
    #pragma unroll
    for (int off = 32; off > 0; off >>= 1) ss += __shfl_down(ss, off);
    ss = __shfl(ss, 0);
    float scale = g[row] / sqrtf(ss);
    float* wr = w + (size_t)row * fanin;
    for (int i = threadIdx.x; i < fanin; i += 64) wr[i] = vr[i] * scale;
}

// ---------------------------------------------------------------------------
// Fused conv3x3(SAME) + IAF + 2x2 avgpool, LDS-staged, register-prefetched.
// Block = 256 threads = one (b, row-strip) x SEGS c-groups; all SEGS c-groups
// share ONE staged frame strip (stage once per block per t).
// Pipeline per t: [write prefetched regs -> LDS] barrier, issue loads for t+1
// (in flight during compute), compute t from LDS, barrier.
// Per-(pixel,c_out) fmaf order is (ci,ky,kx) — identical floats & ordering to
// round 3 -> bitwise-identical spikes (absmax margin is tight).
// Template: CIN,H,COUT, CG=c_outs/thread, ST=LDS row stride, SP=pooled px/strip.
// ---------------------------------------------------------------------------
template<int CIN, int H, int COUT, int CG, int ST, int SP>
__launch_bounds__(256)
__global__ void conv_iaf_pool(const float* __restrict__ in, const float* __restrict__ w,
                              float* __restrict__ out, int B, int T) {
    constexpr int Hp    = H / 2;
    constexpr int PP    = Hp * Hp;
    constexpr int NCG   = COUT / CG;
    constexpr int TPS   = SP * 4;          // threads per (strip, c-group) segment
    constexpr int SEGS  = 256 / TPS;       // c-groups per block (share the stage)
    constexpr int STRIPS= PP / SP;
    constexpr int CGB   = NCG / SEGS;      // c-group-blocks per (b, strip)
    constexpr int PR    = SP / Hp;         // pooled rows per strip
    constexpr int RR    = 2 * PR + 2;      // staged conv rows (with halo)
    constexpr int SLAB  = CIN * RR * ST;
    constexpr int E     = CIN * RR * (H + 2);
    constexpr int ITERS = (E + 255) / 256;
    __shared__ float slab[SLAB];

    const int tid   = threadIdx.x;
    const int bx    = blockIdx.x;
    const int cgb   = bx % CGB;
    const int strip = (bx / CGB) % STRIPS;
    const int b     = bx / (CGB * STRIPS);

    const int seg  = tid / TPS;            // wave-uniform (TPS is 64 or 128)
    const int l    = tid % TPS;
    const int q    = l & 3;
    const int pixl = l >> 2;
    const int pix  = strip * SP + pixl;
    const int yp   = pix / Hp, xp = pix % Hp;
    const int y    = 2 * yp + (q >> 1), x = 2 * xp + (q & 1);
    const int y0   = 2 * (strip * PR);     // first conv row of strip

    const int c0 = __builtin_amdgcn_readfirstlane((cgb * SEGS + seg) * CG);
    const float* __restrict__ wu = w + (size_t)c0 * (CIN * 9);

    // ---- staging offsets (block-level, all 256 threads participate) ----
    int goff[ITERS], loff[ITERS];
    #pragma unroll
    for (int i = 0; i < ITERS; ++i) {
        const int idx = tid + i * 256;
        const int j  = idx % (H + 2);
        const int rr = (idx / (H + 2)) % RR;
        const int ci = idx / ((H + 2) * RR);
        const int gy = y0 - 1 + rr, gx = j - 1;
        const bool ok = (idx < E) && ((unsigned)gy < (unsigned)H) && ((unsigned)gx < (unsigned)H);
        goff[i] = ok ? (ci * (H * H) + gy * H + gx) : -1;
        loff[i] = (idx < E) ? (ci * (RR * ST) + rr * ST + j) : -1;
    }

    // ---- weights resident in VGPRs when small enough (L0) ----
    constexpr bool WREG = (CG * CIN * 9) <= 80;
    float wreg[WREG ? (CG * CIN * 9) : 1];
    if constexpr (WREG) {
        #pragma unroll
        for (int i = 0; i < CG * CIN * 9; ++i) wreg[i] = wu[i];
    }

    const float* pbase = slab + (y - y0) * ST + x;

    float v[CG];
    #pragma unroll
    for (int c = 0; c < CG; ++c) v[c] = 0.f;

    // ---- prefetch frame t=0 into registers ----
    float pf[ITERS];
    {
        const float* inb = in + (size_t)(b * T) * (CIN * H * H);
        #pragma unroll
        for (int i = 0; i < ITERS; ++i)
            pf[i] = (goff[i] >= 0) ? inb[goff[i]] : 0.f;
    }

    for (int t = 0; t < T; ++t) {
        __syncthreads();                       // prev-t LDS readers done
        #pragma unroll
        for (int i = 0; i < ITERS; ++i)
            if (loff[i] >= 0) slab[loff[i]] = pf[i];
        __syncthreads();                       // LDS ready

        // issue loads for t+1 now; they stay in flight during compute
        if (t + 1 < T) {
            const float* inb = in + (size_t)(b * T + t + 1) * (CIN * H * H);
            #pragma unroll
            for (int i = 0; i < ITERS; ++i)
                pf[i] = (goff[i] >= 0) ? inb[goff[i]] : 0.f;
        }

        float acc[CG];
        #pragma unroll
        for (int c = 0; c < CG; ++c) acc[c] = 0.f;

        constexpr int CIU = (CIN < 8) ? CIN : 8;
        for (int cio = 0; cio < CIN; cio += CIU) {
            #pragma unroll
            for (int cii = 0; cii < CIU; ++cii) {
                const int ci = cio + cii;
                const float* pb = pbase + ci * (RR * ST);
                float p[9];
                #pragma unroll
                for (int r = 0; r < 3; ++r)
                    #pragma unroll
                    for (int cc = 0; cc < 3; ++cc)
                        p[r * 3 + cc] = pb[r * ST + cc];
                #pragma unroll
                for (int c = 0; c < CG; ++c) {
                    #pragma unroll
                    for (int k = 0; k < 9; ++k) {
                        const float wv = WREG ? wreg[(c * CIN + ci) * 9 + k]
                                              : wu[(size_t)c * (CIN * 9) + ci * 9 + k];
                        acc[c] = fmaf(p[k], wv, acc[c]);
                    }
                }
            }
        }

        #pragma unroll
        for (int c = 0; c < CG; ++c) {
            v[c] += acc[c];
            float s = (v[c] >= THRESH) ? 1.f : 0.f;
            v[c] -= THRESH * s;
            float sum = s;                      // exact 0/1 sums
            sum += __shfl_xor(sum, 1);
            sum += __shfl_xor(sum, 2);
            if (q == 0)
                out[((size_t)(b * T + t) * COUT + (c0 + c)) * PP + pix] = 0.25f * sum;
        }
    }
}

// ---------------------------------------------------------------------------
// Linear: out (1600, 11) = h (1600, 1024) @ w^T (11, 1024)
// ---------------------------------------------------------------------------
__global__ void linear_kernel(const float* __restrict__ h, const float* __restrict__ w,
                              float* __restrict__ out) {
    __shared__ float hs[1024];
    __shared__ float part[16][17];
    const int n = blockIdx.x;
    for (int i = threadIdx.x; i < 1024; i += blockDim.x)
        hs[i] = h[(size_t)n * 1024 + i];
    __syncthreads();
    const int j = threadIdx.x & 15, ch = threadIdx.x >> 4;
    float acc = 0.f;
    if (j < 11) {
        const float* wr = w + (size_t)j * 1024 + ch * 64;
        const float* hh = hs + ch * 64;
        #pragma unroll 8
        for (int k = 0; k < 64; ++k) acc = fmaf(hh[k], wr[k], acc);
    }
    part[j][ch] = acc;
    __syncthreads();
    if (threadIdx.x < 11) {
        float s = 0.f;
        #pragma unroll
        for (int cc = 0; cc < 16; ++cc) s += part[threadIdx.x][cc];
        out[(size_t)n * 11 + threadIdx.x] = s;
    }
}

// ---------------------------------------------------------------------------
extern "C" void kernel_launch(void* const* d_in, const int* in_sizes, int n_in,
                              void* d_out, int out_size, void* d_ws, size_t ws_size,
                              hipStream_t stream) {
    const int B = 32, T = 50;

    const float* x   = (const float*)d_in[0];
    const float* c0v = (const float*)d_in[1];
    const float* c0g = (const float*)d_in[2];
    const float* c1v = (const float*)d_in[3];
    const float* c1g = (const float*)d_in[4];
    const float* c2v = (const float*)d_in[5];
    const float* c2g = (const float*)d_in[6];
    const float* c3v = (const float*)d_in[7];
    const float* c3g = (const float*)d_in[8];
    const float* lv  = (const float*)d_in[9];
    const float* lg  = (const float*)d_in[10];
    float* out = (float*)d_out;

    // Workspace layout (floats)
    float* ws = (float*)d_ws;
    float* w0 = ws;                    // 8*2*9     = 144
    float* w1 = w0 + 144;              // 16*8*9    = 1152
    float* w2 = w1 + 1152;             // 32*16*9   = 4608
    float* w3 = w2 + 4608;             // 64*32*9   = 18432
    float* wl = w3 + 18432;            // 11*1024   = 11264
    float* bufA = ws + 40960;                  // L0 out: 1600*8*32*32  = 13,107,200
    float* bufB = bufA + (size_t)13107200;     // L1 out: 1600*16*16*16 =  6,553,600
    // L2 out (3,276,800) reuses bufA; L3 out (1,638,400) reuses bufB.

    wnorm_kernel<<<8,  64, 0, stream>>>(c0v, c0g, w0, 2 * 9);
    wnorm_kernel<<<16, 64, 0, stream>>>(c1v, c1g, w1, 8 * 9);
    wnorm_kernel<<<32, 64, 0, stream>>>(c2v, c2g, w2, 16 * 9);
    wnorm_kernel<<<64, 64, 0, stream>>>(c3v, c3g, w3, 32 * 9);
    wnorm_kernel<<<11, 64, 0, stream>>>(lv,  lg,  wl, 1024);

    // <CIN,H,COUT,CG,ST,SP>; blocks = B * (PP/SP) * (COUT/CG)/(64/SP)
    conv_iaf_pool<2, 64, 8, 4, 66, 32><<<1024, 256, 0, stream>>>(x, w0, bufA, B, T);     // L0
    conv_iaf_pool<8, 32, 16, 2, 34, 32><<<1024, 256, 0, stream>>>(bufA, w1, bufB, B, T); // L1
    conv_iaf_pool<16, 16, 32, 2, 24, 32><<<512, 256, 0, stream>>>(bufB, w2, bufA, B, T); // L2
    conv_iaf_pool<32, 8, 64, 1, 12, 16><<<512, 256, 0, stream>>>(bufA, w3, bufB, B, T);  // L3

    linear_kernel<<<B * T, 256, 0, stream>>>(bufB, wl, out);
}

// Round 5
// 809.401 us; speedup vs baseline: 3.6089x; 1.0267x over previous
//
#include <hip/hip_runtime.h>

#define THRESH 0.1f

// ---------------------------------------------------------------------------
// Merged weight norm for all 5 tensors: w[row,:] = g[row]*v[row,:]/||v[row,:]||
// One 64-thread block per row; per-row math identical to previous rounds
// (same wave-64 reduction order -> identical weight bits).
// rows [0,8): conv0, [8,24): conv1, [24,56): conv2, [56,120): conv3, [120,131): lin
// ---------------------------------------------------------------------------
__global__ void wnorm_all(const float* __restrict__ c0v, const float* __restrict__ c0g,
                          const float* __restrict__ c1v, const float* __restrict__ c1g,
                          const float* __restrict__ c2v, const float* __restrict__ c2g,
                          const float* __restrict__ c3v, const float* __restrict__ c3g,
                          const float* __restrict__ lv,  const float* __restrict__ lg,
                          float* __restrict__ w0, float* __restrict__ w1,
                          float* __restrict__ w2, float* __restrict__ w3,
                          float* __restrict__ wl) {
    int rb = blockIdx.x;
    const float *v, *g; float* w; int fanin, row;
    if (rb < 8)        { v = c0v; g = c0g; w = w0; fanin = 18;   row = rb; }
    else if (rb < 24)  { v = c1v; g = c1g; w = w1; fanin = 72;   row = rb - 8; }
    else if (rb < 56)  { v = c2v; g = c2g; w = w2; fanin = 144;  row = rb - 24; }
    else if (rb < 120) { v = c3v; g = c3g; w = w3; fanin = 288;  row = rb - 56; }
    else               { v = lv;  g = lg;  w = wl; fanin = 1024; row = rb - 120; }

    const float* vr = v + (size_t)row * fanin;
    float ss = 0.f;
    for (int i = threadIdx.x; i < fanin; i += 64) { float x = vr[i]; ss = fmaf(x, x, ss); }
    #pragma unroll
    for (int off = 32; off > 0; off >>= 1) ss += __shfl_down(ss, off);
    ss = __shfl(ss, 0);
    float scale = g[row] / sqrtf(ss);
    float* wr = w + (size_t)row * fanin;
    for (int i = threadIdx.x; i < fanin; i += 64) wr[i] = vr[i] * scale;
}

// ---------------------------------------------------------------------------
// Fused conv3x3(SAME) + IAF + 2x2 avgpool; double-buffered LDS, register
// prefetch, one barrier per timestep, XCD-swizzled block index.
// Block = BDIM threads = one (b, row-strip) x SEGS c-groups sharing the stage.
// LDS layout = exact staging linear index (ST = H+2): staging write address is
// the thread's linear index -> no loff array, conflict-free writes.
// Per-(pixel,c_out) fmaf order (ci,ky,kx) identical to rounds 3/4 ->
// bitwise-identical spikes (absmax margin is tight, do not reorder).
// ---------------------------------------------------------------------------
template<int CIN, int H, int COUT, int CG, int SP, int BDIM>
__launch_bounds__(BDIM)
__global__ void conv_iaf_pool(const float* __restrict__ in, const float* __restrict__ w,
                              float* __restrict__ out, int B, int T) {
    constexpr int Hp     = H / 2;
    constexpr int PP     = Hp * Hp;
    constexpr int NCG    = COUT / CG;
    constexpr int TPS    = SP * 4;            // threads per (strip, c-group) segment
    constexpr int SEGS   = BDIM / TPS;        // c-groups sharing this block's stage
    constexpr int STRIPS = PP / SP;
    constexpr int CGB    = NCG / SEGS;        // c-group-blocks per (b, strip)
    constexpr int PR     = SP / Hp;           // pooled rows per strip
    constexpr int RR     = 2 * PR + 2;        // staged conv rows (with halo)
    constexpr int ST     = H + 2;             // LDS row stride = staged row width
    constexpr int E      = CIN * RR * ST;     // staged elements (== slab size)
    constexpr int ITERS  = (E + BDIM - 1) / BDIM;
    constexpr int SLABP  = ITERS * BDIM;      // padded so writes are unconditional
    __shared__ float slab[2][SLABP];

    const int tid = threadIdx.x;

    // XCD swizzle: cluster same-b blocks on one XCD (assignment ~ bx % 8)
    const int G  = gridDim.x;
    const int bx = blockIdx.x;
    const int p  = (bx & 7) * (G >> 3) + (bx >> 3);

    const int cgb   = p % CGB;
    const int strip = (p / CGB) % STRIPS;
    const int b     = p / (CGB * STRIPS);

    const int seg  = tid / TPS;               // wave-uniform (TPS is 64/128/256)
    const int l    = tid % TPS;
    const int q    = l & 3;
    const int pixl = l >> 2;
    const int pix  = strip * SP + pixl;
    const int yp   = pix / Hp, xp = pix % Hp;
    const int y    = 2 * yp + (q >> 1), x = 2 * xp + (q & 1);
    const int y0   = 2 * (strip * PR);        // first conv row of strip

    const int c0 = __builtin_amdgcn_readfirstlane((cgb * SEGS + seg) * CG);
    const float* __restrict__ wu = w + (size_t)c0 * (CIN * 9);

    // ---- staging global offsets (LDS offset == linear index, no array) ----
    int goff[ITERS];
    #pragma unroll
    for (int i = 0; i < ITERS; ++i) {
        const int idx = tid + i * BDIM;
        const int j  = idx % ST;
        const int rr = (idx / ST) % RR;
        const int ci = idx / (ST * RR);
        const int gy = y0 - 1 + rr, gx = j - 1;
        const bool ok = (idx < E) && ((unsigned)gy < (unsigned)H) && ((unsigned)gx < (unsigned)H);
        goff[i] = ok ? (ci * (H * H) + gy * H + gx) : -1;
    }

    // ---- weights resident in VGPRs when small (L0) ----
    constexpr bool WREG = (CG * CIN * 9) <= 80;
    float wreg[WREG ? (CG * CIN * 9) : 1];
    if constexpr (WREG) {
        #pragma unroll
        for (int i = 0; i < CG * CIN * 9; ++i) wreg[i] = wu[i];
    }

    const int po = (y - y0) * ST + x;         // patch base offset within slab

    float v[CG];
    #pragma unroll
    for (int c = 0; c < CG; ++c) v[c] = 0.f;

    // ---- prologue: stage frame 0, prefetch frame 1 ----
    float pf[ITERS];
    {
        const float* inb = in + (size_t)(b * T) * (CIN * H * H);
        #pragma unroll
        for (int i = 0; i < ITERS; ++i)
            pf[i] = (goff[i] >= 0) ? inb[goff[i]] : 0.f;
        #pragma unroll
        for (int i = 0; i < ITERS; ++i)
            slab[0][tid + i * BDIM] = pf[i];
        const float* inb1 = in + (size_t)(b * T + 1) * (CIN * H * H);
        #pragma unroll
        for (int i = 0; i < ITERS; ++i)
            pf[i] = (goff[i] >= 0) ? inb1[goff[i]] : 0.f;
    }
    __syncthreads();

    for (int t = 0; t < T; ++t) {
        // write frame t+1 into the other slab (its last readers synced at t-1)
        if (t + 1 < T) {
            #pragma unroll
            for (int i = 0; i < ITERS; ++i)
                slab[(t + 1) & 1][tid + i * BDIM] = pf[i];
        }
        // issue global loads for frame t+2; in flight during compute
        if (t + 2 < T) {
            const float* inb = in + (size_t)(b * T + t + 2) * (CIN * H * H);
            #pragma unroll
            for (int i = 0; i < ITERS; ++i)
                pf[i] = (goff[i] >= 0) ? inb[goff[i]] : 0.f;
        }

        const float* sl = slab[t & 1] + po;
        float acc[CG];
        #pragma unroll
        for (int c = 0; c < CG; ++c) acc[c] = 0.f;

        constexpr int CIU = (CIN < 8) ? CIN : 8;
        for (int cio = 0; cio < CIN; cio += CIU) {
            #pragma unroll
            for (int cii = 0; cii < CIU; ++cii) {
                const int ci = cio + cii;
                const float* pb = sl + ci * (RR * ST);
                float pch[9];
                #pragma unroll
                for (int r = 0; r < 3; ++r)
                    #pragma unroll
                    for (int cc = 0; cc < 3; ++cc)
                        pch[r * 3 + cc] = pb[r * ST + cc];
                #pragma unroll
                for (int c = 0; c < CG; ++c) {
                    #pragma unroll
                    for (int k = 0; k < 9; ++k) {
                        const float wv = WREG ? wreg[(c * CIN + ci) * 9 + k]
                                              : wu[(size_t)c * (CIN * 9) + ci * 9 + k];
                        acc[c] = fmaf(pch[k], wv, acc[c]);
                    }
                }
            }
        }

        #pragma unroll
        for (int c = 0; c < CG; ++c) {
            v[c] += acc[c];
            float s = (v[c] >= THRESH) ? 1.f : 0.f;
            v[c] -= THRESH * s;
            float sum = s;                     // exact 0/1 sums
            sum += __shfl_xor(sum, 1);
            sum += __shfl_xor(sum, 2);
            if (q == 0)
                out[((size_t)(b * T + t) * COUT + (c0 + c)) * PP + pix] = 0.25f * sum;
        }
        __syncthreads();                       // single barrier per timestep
    }
}

// ---------------------------------------------------------------------------
// Linear: out (1600, 11) = h (1600, 1024) @ w^T (11, 1024)
// ---------------------------------------------------------------------------
__global__ void linear_kernel(const float* __restrict__ h, const float* __restrict__ w,
                              float* __restrict__ out) {
    __shared__ float hs[1024];
    __shared__ float part[16][17];
    const int n = blockIdx.x;
    for (int i = threadIdx.x; i < 1024; i += blockDim.x)
        hs[i] = h[(size_t)n * 1024 + i];
    __syncthreads();
    const int j = threadIdx.x & 15, ch = threadIdx.x >> 4;
    float acc = 0.f;
    if (j < 11) {
        const float* wr = w + (size_t)j * 1024 + ch * 64;
        const float* hh = hs + ch * 64;
        #pragma unroll 8
        for (int k = 0; k < 64; ++k) acc = fmaf(hh[k], wr[k], acc);
    }
    part[j][ch] = acc;
    __syncthreads();
    if (threadIdx.x < 11) {
        float s = 0.f;
        #pragma unroll
        for (int cc = 0; cc < 16; ++cc) s += part[threadIdx.x][cc];
        out[(size_t)n * 11 + threadIdx.x] = s;
    }
}

// ---------------------------------------------------------------------------
extern "C" void kernel_launch(void* const* d_in, const int* in_sizes, int n_in,
                              void* d_out, int out_size, void* d_ws, size_t ws_size,
                              hipStream_t stream) {
    const int B = 32, T = 50;

    const float* x   = (const float*)d_in[0];
    const float* c0v = (const float*)d_in[1];
    const float* c0g = (const float*)d_in[2];
    const float* c1v = (const float*)d_in[3];
    const float* c1g = (const float*)d_in[4];
    const float* c2v = (const float*)d_in[5];
    const float* c2g = (const float*)d_in[6];
    const float* c3v = (const float*)d_in[7];
    const float* c3g = (const float*)d_in[8];
    const float* lv  = (const float*)d_in[9];
    const float* lg  = (const float*)d_in[10];
    float* out = (float*)d_out;

    // Workspace layout (floats)
    float* ws = (float*)d_ws;
    float* w0 = ws;                    // 8*2*9     = 144
    float* w1 = w0 + 144;              // 16*8*9    = 1152
    float* w2 = w1 + 1152;             // 32*16*9   = 4608
    float* w3 = w2 + 4608;             // 64*32*9   = 18432
    float* wl = w3 + 18432;            // 11*1024   = 11264
    float* bufA = ws + 40960;                  // L0 out: 1600*8*32*32  = 13,107,200
    float* bufB = bufA + (size_t)13107200;     // L1 out: 1600*16*16*16 =  6,553,600
    // L2 out (3,276,800) reuses bufA; L3 out (1,638,400) reuses bufB.

    wnorm_all<<<131, 64, 0, stream>>>(c0v, c0g, c1v, c1g, c2v, c2g, c3v, c3g,
                                      lv, lg, w0, w1, w2, w3, wl);

    // <CIN,H,COUT,CG,SP,BDIM>  — all layers: 1024 blocks (4 per CU)
    conv_iaf_pool<2, 64, 8, 4, 32, 256><<<1024, 256, 0, stream>>>(x, w0, bufA, B, T);     // L0
    conv_iaf_pool<8, 32, 16, 2, 32, 256><<<1024, 256, 0, stream>>>(bufA, w1, bufB, B, T); // L1
    conv_iaf_pool<16, 16, 32, 1, 32, 256><<<1024, 256, 0, stream>>>(bufB, w2, bufA, B, T);// L2
    conv_iaf_pool<32, 8, 64, 1, 16, 128><<<1024, 128, 0, stream>>>(bufA, w3, bufB, B, T); // L3

    linear_kernel<<<B * T, 256, 0, stream>>>(bufB, wl, out);
}

// Round 6
// 717.432 us; speedup vs baseline: 4.0716x; 1.1282x over previous
//
#include <hip/hip_runtime.h>

#define THRESH 0.1f

typedef float f4 __attribute__((ext_vector_type(4)));

// ---------------------------------------------------------------------------
// Merged weight norm (per-row math identical to all prior rounds).
// rows [0,8): conv0, [8,24): conv1, [24,56): conv2, [56,120): conv3, [120,131): lin
// ---------------------------------------------------------------------------
__global__ void wnorm_all(const float* __restrict__ c0v, const float* __restrict__ c0g,
                          const float* __restrict__ c1v, const float* __restrict__ c1g,
                          const float* __restrict__ c2v, const float* __restrict__ c2g,
                          const float* __restrict__ c3v, const float* __restrict__ c3g,
                          const float* __restrict__ lv,  const float* __restrict__ lg,
                          float* __restrict__ w0, float* __restrict__ w1,
                          float* __restrict__ w2, float* __restrict__ w3,
                          float* __restrict__ wl) {
    int rb = blockIdx.x;
    const float *v, *g; float* w; int fanin, row;
    if (rb < 8)        { v = c0v; g = c0g; w = w0; fanin = 18;   row = rb; }
    else if (rb < 24)  { v = c1v; g = c1g; w = w1; fanin = 72;   row = rb - 8; }
    else if (rb < 56)  { v = c2v; g = c2g; w = w2; fanin = 144;  row = rb - 24; }
    else if (rb < 120) { v = c3v; g = c3g; w = w3; fanin = 288;  row = rb - 56; }
    else               { v = lv;  g = lg;  w = wl; fanin = 1024; row = rb - 120; }

    const float* vr = v + (size_t)row * fanin;
    float ss = 0.f;
    for (int i = threadIdx.x; i < fanin; i += 64) { float x = vr[i]; ss = fmaf(x, x, ss); }
    #pragma unroll
    for (int off = 32; off > 0; off >>= 1) ss += __shfl_down(ss, off);
    ss = __shfl(ss, 0);
    float scale = g[row] / sqrtf(ss);
    float* wr = w + (size_t)row * fanin;
    for (int i = threadIdx.x; i < fanin; i += 64) wr[i] = vr[i] * scale;
}

// ---------------------------------------------------------------------------
// Fused conv3x3(SAME) + IAF + 2x2 avgpool; double-buffered LDS, register
// prefetch, one barrier per timestep, XCD-swizzled block index.
// QUAD path (CIN%4==0): LDS layout [row][col][ci], ci padded to CIP=CIN+4
// -> ds_read_b128 fetches 4 ci per patch position (4x fewer LDS issues),
//    bank-group factor (CIP/4 mod 8) odd -> wave64 reads hit the 8-clk floor.
// FMA order per (pixel,c_out) remains (ci ascending, k ascending) with the
// same staged values -> bitwise-identical spikes vs rounds 3-5.
// ---------------------------------------------------------------------------
template<int CIN, int H, int COUT, int CG, int SP, int BDIM>
__launch_bounds__(BDIM)
__global__ void conv_iaf_pool(const float* __restrict__ in, const float* __restrict__ w,
                              float* __restrict__ out, int B, int T) {
    constexpr int Hp     = H / 2;
    constexpr int PP     = Hp * Hp;
    constexpr int NCG    = COUT / CG;
    constexpr int TPS    = SP * 4;            // threads per (strip, c-group) segment
    constexpr int SEGS   = BDIM / TPS;        // c-groups sharing this block's stage
    constexpr int STRIPS = PP / SP;
    constexpr int CGB    = NCG / SEGS;        // c-group-blocks per (b, strip)
    constexpr int PR     = SP / Hp;           // pooled rows per strip
    constexpr int RR     = 2 * PR + 2;        // staged conv rows (with halo)
    constexpr int COLS   = H + 2;             // staged row width (with halo)
    constexpr bool QUAD  = (CIN % 4 == 0);
    constexpr int CIP    = QUAD ? (CIN + 4) : 1;   // padded ci stride (words)
    constexpr int E      = CIN * RR * COLS;   // staged elements
    constexpr int ITERS  = (E + BDIM - 1) / BDIM;
    constexpr int SLABN  = QUAD ? (RR * COLS * CIP) : (ITERS * BDIM);
    __shared__ alignas(16) float slab[2][SLABN];

    const int tid = threadIdx.x;

    // XCD swizzle: cluster same-b blocks on one XCD (assignment ~ bx % 8)
    const int G  = gridDim.x;
    const int bx = blockIdx.x;
    const int p  = (bx & 7) * (G >> 3) + (bx >> 3);

    const int cgb   = p % CGB;
    const int strip = (p / CGB) % STRIPS;
    const int b     = p / (CGB * STRIPS);

    const int seg  = tid / TPS;               // wave-uniform (TPS is 64/128/256)
    const int l    = tid % TPS;
    const int q    = l & 3;
    const int pixl = l >> 2;
    const int pix  = strip * SP + pixl;
    const int yp   = pix / Hp, xp = pix % Hp;
    const int y    = 2 * yp + (q >> 1), x = 2 * xp + (q & 1);
    const int y0   = 2 * (strip * PR);        // first conv row of strip
    const int yl   = y - y0;                  // patch top row within slab

    const int c0 = __builtin_amdgcn_readfirstlane((cgb * SEGS + seg) * CG);
    const float* __restrict__ wu = w + (size_t)c0 * (CIN * 9);

    // ---- staging offsets (same coalesced global mapping as rounds 3-5) ----
    int goff[ITERS], loff[ITERS];
    #pragma unroll
    for (int i = 0; i < ITERS; ++i) {
        const int idx = tid + i * BDIM;
        const int j  = idx % COLS;
        const int rr = (idx / COLS) % RR;
        const int ci = idx / (COLS * RR);
        const int gy = y0 - 1 + rr, gx = j - 1;
        const bool ok = (idx < E) && ((unsigned)gy < (unsigned)H) && ((unsigned)gx < (unsigned)H);
        goff[i] = ok ? (ci * (H * H) + gy * H + gx) : -1;
        loff[i] = (idx < E) ? (QUAD ? ((rr * COLS + j) * CIP + ci) : idx) : -1;
    }

    // ---- weights resident in VGPRs when small (L0) ----
    constexpr bool WREG = (CG * CIN * 9) <= 80;
    float wreg[WREG ? (CG * CIN * 9) : 1];
    if constexpr (WREG) {
        #pragma unroll
        for (int i = 0; i < CG * CIN * 9; ++i) wreg[i] = wu[i];
    }

    float v[CG];
    #pragma unroll
    for (int c = 0; c < CG; ++c) v[c] = 0.f;

    // ---- prologue: stage frame 0, prefetch frame 1 ----
    float pf[ITERS];
    {
        const float* inb = in + (size_t)(b * T) * (CIN * H * H);
        #pragma unroll
        for (int i = 0; i < ITERS; ++i)
            pf[i] = (goff[i] >= 0) ? inb[goff[i]] : 0.f;
        #pragma unroll
        for (int i = 0; i < ITERS; ++i)
            if (loff[i] >= 0) slab[0][loff[i]] = pf[i];
        const float* inb1 = in + (size_t)(b * T + 1) * (CIN * H * H);
        #pragma unroll
        for (int i = 0; i < ITERS; ++i)
            pf[i] = (goff[i] >= 0) ? inb1[goff[i]] : 0.f;
    }
    __syncthreads();

    for (int t = 0; t < T; ++t) {
        // write frame t+1 into the other slab (its last readers synced at t-1)
        if (t + 1 < T) {
            #pragma unroll
            for (int i = 0; i < ITERS; ++i)
                if (loff[i] >= 0) slab[(t + 1) & 1][loff[i]] = pf[i];
        }
        // issue global loads for frame t+2; in flight during compute
        if (t + 2 < T) {
            const float* inb = in + (size_t)(b * T + t + 2) * (CIN * H * H);
            #pragma unroll
            for (int i = 0; i < ITERS; ++i)
                pf[i] = (goff[i] >= 0) ? inb[goff[i]] : 0.f;
        }

        const float* sl = slab[t & 1];
        float acc[CG];
        #pragma unroll
        for (int c = 0; c < CG; ++c) acc[c] = 0.f;

        if constexpr (QUAD) {
            const int pbase = (yl * COLS + x) * CIP;
            #pragma unroll
            for (int cq = 0; cq < CIN / 4; ++cq) {
                f4 P[9];
                #pragma unroll
                for (int dr = 0; dr < 3; ++dr)
                    #pragma unroll
                    for (int dc = 0; dc < 3; ++dc)
                        P[dr * 3 + dc] = *reinterpret_cast<const f4*>(
                            sl + pbase + (dr * COLS + dc) * CIP + 4 * cq);
                #pragma unroll
                for (int cid = 0; cid < 4; ++cid) {
                    const int ci = 4 * cq + cid;
                    #pragma unroll
                    for (int c = 0; c < CG; ++c) {
                        #pragma unroll
                        for (int k = 0; k < 9; ++k) {
                            const float wv = WREG ? wreg[(c * CIN + ci) * 9 + k]
                                                  : wu[(size_t)c * (CIN * 9) + ci * 9 + k];
                            acc[c] = fmaf(P[k][cid], wv, acc[c]);
                        }
                    }
                }
            }
        } else {
            const float* pb0 = sl + yl * COLS + x;
            #pragma unroll
            for (int ci = 0; ci < CIN; ++ci) {
                const float* pb = pb0 + ci * (RR * COLS);
                float pch[9];
                #pragma unroll
                for (int r = 0; r < 3; ++r)
                    #pragma unroll
                    for (int cc = 0; cc < 3; ++cc)
                        pch[r * 3 + cc] = pb[r * COLS + cc];
                #pragma unroll
                for (int c = 0; c < CG; ++c) {
                    #pragma unroll
                    for (int k = 0; k < 9; ++k) {
                        const float wv = WREG ? wreg[(c * CIN + ci) * 9 + k]
                                              : wu[(size_t)c * (CIN * 9) + ci * 9 + k];
                        acc[c] = fmaf(pch[k], wv, acc[c]);
                    }
                }
            }
        }

        #pragma unroll
        for (int c = 0; c < CG; ++c) {
            v[c] += acc[c];
            float s = (v[c] >= THRESH) ? 1.f : 0.f;
            v[c] -= THRESH * s;
            float sum = s;                     // exact 0/1 sums
            sum += __shfl_xor(sum, 1);
            sum += __shfl_xor(sum, 2);
            if (q == 0)
                out[((size_t)(b * T + t) * COUT + (c0 + c)) * PP + pix] = 0.25f * sum;
        }
        __syncthreads();                       // single barrier per timestep
    }
}

// ---------------------------------------------------------------------------
// Linear: out (1600, 11) = h (1600, 1024) @ w^T (11, 1024)
// ---------------------------------------------------------------------------
__global__ void linear_kernel(const float* __restrict__ h, const float* __restrict__ w,
                              float* __restrict__ out) {
    __shared__ float hs[1024];
    __shared__ float part[16][17];
    const int n = blockIdx.x;
    for (int i = threadIdx.x; i < 1024; i += blockDim.x)
        hs[i] = h[(size_t)n * 1024 + i];
    __syncthreads();
    const int j = threadIdx.x & 15, ch = threadIdx.x >> 4;
    float acc = 0.f;
    if (j < 11) {
        const float* wr = w + (size_t)j * 1024 + ch * 64;
        const float* hh = hs + ch * 64;
        #pragma unroll 8
        for (int k = 0; k < 64; ++k) acc = fmaf(hh[k], wr[k], acc);
    }
    part[j][ch] = acc;
    __syncthreads();
    if (threadIdx.x < 11) {
        float s = 0.f;
        #pragma unroll
        for (int cc = 0; cc < 16; ++cc) s += part[threadIdx.x][cc];
        out[(size_t)n * 11 + threadIdx.x] = s;
    }
}

// ---------------------------------------------------------------------------
extern "C" void kernel_launch(void* const* d_in, const int* in_sizes, int n_in,
                              void* d_out, int out_size, void* d_ws, size_t ws_size,
                              hipStream_t stream) {
    const int B = 32, T = 50;

    const float* x   = (const float*)d_in[0];
    const float* c0v = (const float*)d_in[1];
    const float* c0g = (const float*)d_in[2];
    const float* c1v = (const float*)d_in[3];
    const float* c1g = (const float*)d_in[4];
    const float* c2v = (const float*)d_in[5];
    const float* c2g = (const float*)d_in[6];
    const float* c3v = (const float*)d_in[7];
    const float* c3g = (const float*)d_in[8];
    const float* lv  = (const float*)d_in[9];
    const float* lg  = (const float*)d_in[10];
    float* out = (float*)d_out;

    // Workspace layout (floats)
    float* ws = (float*)d_ws;
    float* w0 = ws;                    // 8*2*9     = 144
    float* w1 = w0 + 144;              // 16*8*9    = 1152
    float* w2 = w1 + 1152;             // 32*16*9   = 4608
    float* w3 = w2 + 4608;             // 64*32*9   = 18432
    float* wl = w3 + 18432;            // 11*1024   = 11264
    float* bufA = ws + 40960;                  // L0 out: 1600*8*32*32  = 13,107,200
    float* bufB = bufA + (size_t)13107200;     // L1 out: 1600*16*16*16 =  6,553,600
    // L2 out (3,276,800) reuses bufA; L3 out (1,638,400) reuses bufB.

    wnorm_all<<<131, 64, 0, stream>>>(c0v, c0g, c1v, c1g, c2v, c2g, c3v, c3g,
                                      lv, lg, w0, w1, w2, w3, wl);

    // <CIN,H,COUT,CG,SP,BDIM>; blocks = B * STRIPS * CGB
    conv_iaf_pool<2, 64, 8, 4, 32, 256><<<1024, 256, 0, stream>>>(x, w0, bufA, B, T);     // L0
    conv_iaf_pool<8, 32, 16, 2, 32, 256><<<1024, 256, 0, stream>>>(bufA, w1, bufB, B, T); // L1
    conv_iaf_pool<16, 16, 32, 2, 32, 256><<<512, 256, 0, stream>>>(bufB, w2, bufA, B, T); // L2
    conv_iaf_pool<32, 8, 64, 2, 16, 128><<<512, 128, 0, stream>>>(bufA, w3, bufB, B, T);  // L3

    linear_kernel<<<B * T, 256, 0, stream>>>(bufB, wl, out);
}

// Round 7
// 686.851 us; speedup vs baseline: 4.2528x; 1.0445x over previous
//
#include <hip/hip_runtime.h>

#define THRESH 0.1f

typedef float f4 __attribute__((ext_vector_type(4)));
typedef float f2 __attribute__((ext_vector_type(2)));

// ---------------------------------------------------------------------------
// Merged weight norm (per-row math identical to all prior rounds -> same bits).
// rows [0,8): conv0, [8,24): conv1, [24,56): conv2, [56,120): conv3, [120,131): lin
// ---------------------------------------------------------------------------
__global__ void wnorm_all(const float* __restrict__ c0v, const float* __restrict__ c0g,
                          const float* __restrict__ c1v, const float* __restrict__ c1g,
                          const float* __restrict__ c2v, const float* __restrict__ c2g,
                          const float* __restrict__ c3v, const float* __restrict__ c3g,
                          const float* __restrict__ lv,  const float* __restrict__ lg,
                          float* __restrict__ w0, float* __restrict__ w1,
                          float* __restrict__ w2, float* __restrict__ w3,
                          float* __restrict__ wl) {
    int rb = blockIdx.x;
    const float *v, *g; float* w; int fanin, row;
    if (rb < 8)        { v = c0v; g = c0g; w = w0; fanin = 18;   row = rb; }
    else if (rb < 24)  { v = c1v; g = c1g; w = w1; fanin = 72;   row = rb - 8; }
    else if (rb < 56)  { v = c2v; g = c2g; w = w2; fanin = 144;  row = rb - 24; }
    else if (rb < 120) { v = c3v; g = c3g; w = w3; fanin = 288;  row = rb - 56; }
    else               { v = lv;  g = lg;  w = wl; fanin = 1024; row = rb - 120; }

    const float* vr = v + (size_t)row * fanin;
    float ss = 0.f;
    for (int i = threadIdx.x; i < fanin; i += 64) { float x = vr[i]; ss = fmaf(x, x, ss); }
    #pragma unroll
    for (int off = 32; off > 0; off >>= 1) ss += __shfl_down(ss, off);
    ss = __shfl(ss, 0);
    float scale = g[row] / sqrtf(ss);
    float* wr = w + (size_t)row * fanin;
    for (int i = threadIdx.x; i < fanin; i += 64) wr[i] = vr[i] * scale;
}

// ---------------------------------------------------------------------------
// Fused conv3x3(SAME) + IAF + 2x2 avgpool.
// Row-major lane->pixel map (wave = WY rows x WX cols); pool partners l^1/l^WX
// with the same (s0+s1)+(s2+s3) association as prior rounds (bitwise ident).
// LDS layout [staged_row][staged_col][ci] with CIP=CIN+4 (odd quad stride ->
// conflict-free ds_read_b128 / ds_write_b128). x-halo = zero columns, y-halo
// rows staged (zeros at frame border) -> no masks in the compute loop; staged
// values identical to reference zero-padding. Staging: 4 coalesced b32 global
// loads (one per ci of a quad) -> 1 ds_write_b128; double-buffered, t+2
// register prefetch, one barrier per timestep. Per-(pixel,c_out) fmaf order
// is (ci ascending, k ascending) — identical to rounds 3-6.
// ---------------------------------------------------------------------------
template<int CIN, int H, int COUT, int CG, int WX, int SEGS, int BDIM, int CIP>
__launch_bounds__(BDIM)
__global__ void conv_iaf_pool(const float* __restrict__ in, const float* __restrict__ w,
                              float* __restrict__ out, int B, int T) {
    constexpr int Hp   = H / 2;
    constexpr int PP   = Hp * Hp;
    constexpr int HH   = H * H;
    constexpr int WY   = 64 / WX;          // rows per wave
    constexpr int NW   = BDIM / 64;
    constexpr int NWps = NW / SEGS;        // waves per c-group
    constexpr int XW   = H / WX;           // waves across x (L0: 2, else 1)
    constexpr int YWV  = NWps / XW;        // waves down
    constexpr int RPB  = YWV * WY;         // conv rows per block
    constexpr int STRIPS = H / RPB;
    constexpr int CGRP = COUT / (CG * SEGS);
    constexpr int SR   = RPB + 2;          // staged rows (with halo)
    constexpr int COLS = H + 2;            // staged cols (with halo)
    constexpr int SLABN = SR * COLS * CIP;
    constexpr int R0   = (RPB == H) ? 1 : 0;   // whole-frame: skip zero rows
    constexpr int NR   = (RPB == H) ? H : SR;  // staged-row iteration count
    constexpr bool QUAD = (CIN % 4 == 0);
    constexpr int CPW  = QUAD ? 4 : 2;     // channels per staged vector
    constexpr int NCQ  = CIN / CPW;
    constexpr int NU   = NR * H * NCQ;     // staging vector units per t
    constexpr int ITERS = (NU + BDIM - 1) / BDIM;

    __shared__ alignas(16) float slab[2][SLABN];

    const int tid = threadIdx.x;
    const int G = gridDim.x, bx = blockIdx.x;
    const int pb = (bx & 7) * (G >> 3) + (bx >> 3);   // XCD clustering
    const int cgb   = pb % CGRP;
    const int strip = (pb / CGRP) % STRIPS;
    const int b     = pb / (CGRP * STRIPS);

    const int wid = tid >> 6, l = tid & 63;
    const int seg = wid / NWps;
    const int wl  = wid % NWps;
    const int xw = wl % XW, yw = wl / XW;
    const int xl = l % WX, ylw = l / WX;
    const int x  = xw * WX + xl;
    const int yy = yw * WY + ylw;          // row within block strip
    const int y0 = strip * RPB;
    const int y  = y0 + yy;

    const int c0 = __builtin_amdgcn_readfirstlane((cgb * SEGS + seg) * CG);
    const float* __restrict__ wu = w + (size_t)c0 * (CIN * 9);

    // patch base addresses (word offsets; staged row yy+dr, staged col x+dc)
    int addrw[9];
    #pragma unroll
    for (int dr = 0; dr < 3; ++dr)
        #pragma unroll
        for (int dc = 0; dc < 3; ++dc)
            addrw[dr * 3 + dc] = ((yy + dr) * COLS + (x + dc)) * CIP;

    // staging unit maps (computed once; lane-invariant over t)
    int goff[ITERS], loff[ITERS];
    #pragma unroll
    for (int i = 0; i < ITERS; ++i) {
        const int idx = tid + i * BDIM;
        const int gx  = idx % H;
        const int rr0 = (idx / H) % NR;
        const int cq  = idx / (H * NR);
        const int rr  = R0 + rr0;          // staged row index
        const int gy  = y0 - 1 + rr;       // frame row
        const bool ok = (idx < NU) && (gy >= 0) && (gy < H);
        goff[i] = ok ? (cq * CPW * HH + gy * H + gx) : -1;
        loff[i] = ok ? ((rr * COLS + (gx + 1)) * CIP + cq * CPW) : -1;
    }

    constexpr bool WREG = (CG * CIN * 9) <= 80;    // L0 only
    float wreg[WREG ? (CG * CIN * 9) : 1];
    if constexpr (WREG) {
        #pragma unroll
        for (int i = 0; i < CG * CIN * 9; ++i) wreg[i] = wu[i];
    }

    // zero both buffers (covers halo rows/cols; interior overwritten per t)
    for (int i = tid; i < 2 * SLABN; i += BDIM) (&slab[0][0])[i] = 0.f;
    __syncthreads();

    float vmem[CG];
    #pragma unroll
    for (int c = 0; c < CG; ++c) vmem[c] = 0.f;

    f4 pf[ITERS];
    #define GATHER(inb)                                                         \
        _Pragma("unroll")                                                       \
        for (int i = 0; i < ITERS; ++i) {                                       \
            const int g_ = goff[i];                                             \
            f4 r_ = {0.f, 0.f, 0.f, 0.f};                                       \
            if (g_ >= 0) {                                                      \
                r_.x = (inb)[g_]; r_.y = (inb)[g_ + HH];                        \
                if constexpr (QUAD) { r_.z = (inb)[g_ + 2*HH]; r_.w = (inb)[g_ + 3*HH]; } \
            }                                                                   \
            pf[i] = r_;                                                         \
        }
    #define STAGE(buf)                                                          \
        _Pragma("unroll")                                                       \
        for (int i = 0; i < ITERS; ++i) {                                       \
            const int lo = loff[i];                                             \
            if (lo >= 0) {                                                      \
                if constexpr (QUAD) *(f4*)(&slab[buf][lo]) = pf[i];             \
                else { f2 v2_; v2_.x = pf[i].x; v2_.y = pf[i].y;                \
                       *(f2*)(&slab[buf][lo]) = v2_; }                          \
            }                                                                   \
        }

    {   // prologue: stage frame 0, prefetch frame 1
        const float* inb0 = in + (size_t)(b * T) * (CIN * HH);
        GATHER(inb0)
        STAGE(0)
        const float* inb1 = in + (size_t)(b * T + 1) * (CIN * HH);
        GATHER(inb1)
    }
    __syncthreads();

    for (int t = 0; t < T; ++t) {
        if (t + 1 < T) { STAGE((t + 1) & 1) }
        if (t + 2 < T) {
            const float* inb = in + (size_t)(b * T + t + 2) * (CIN * HH);
            GATHER(inb)
        }

        const float* sl = &slab[t & 1][0];
        float acc[CG];
        #pragma unroll
        for (int c = 0; c < CG; ++c) acc[c] = 0.f;

        if constexpr (QUAD) {
            #pragma unroll
            for (int cq = 0; cq < NCQ; ++cq) {
                f4 P[9];
                #pragma unroll
                for (int k = 0; k < 9; ++k)
                    P[k] = *(const f4*)(sl + addrw[k] + 4 * cq);
                #pragma unroll
                for (int cid = 0; cid < 4; ++cid) {
                    const int ci = cq * 4 + cid;
                    #pragma unroll
                    for (int c = 0; c < CG; ++c)
                        #pragma unroll
                        for (int k = 0; k < 9; ++k)
                            acc[c] = fmaf(P[k][cid],
                                          WREG ? wreg[(c * CIN + ci) * 9 + k]
                                               : wu[(size_t)(c * CIN + ci) * 9 + k],
                                          acc[c]);
                }
            }
        } else {
            f2 P[9];
            #pragma unroll
            for (int k = 0; k < 9; ++k)
                P[k] = *(const f2*)(sl + addrw[k]);
            #pragma unroll
            for (int cid = 0; cid < 2; ++cid)
                #pragma unroll
                for (int c = 0; c < CG; ++c)
                    #pragma unroll
                    for (int k = 0; k < 9; ++k)
                        acc[c] = fmaf(P[k][cid],
                                      WREG ? wreg[(c * CIN + cid) * 9 + k]
                                           : wu[(size_t)(c * CIN + cid) * 9 + k],
                                      acc[c]);
        }

        #pragma unroll
        for (int c = 0; c < CG; ++c) {
            vmem[c] += acc[c];
            float s = (vmem[c] >= THRESH) ? 1.f : 0.f;
            vmem[c] -= THRESH * s;
            float sum = s;                         // exact 0/1 sums
            sum += __shfl_xor(sum, 1);             // (s0+s1)
            sum += __shfl_xor(sum, WX);            // + (s2+s3)
            if (((xl | ylw) & 1) == 0)
                out[((size_t)(b * T + t) * COUT + (c0 + c)) * PP + (y >> 1) * Hp + (x >> 1)]
                    = 0.25f * sum;
        }
        __syncthreads();                           // single barrier per timestep
    }
    #undef GATHER
    #undef STAGE
}

// ---------------------------------------------------------------------------
// Linear: out (1600, 11) = h (1600, 1024) @ w^T (11, 1024)
// ---------------------------------------------------------------------------
__global__ void linear_kernel(const float* __restrict__ h, const float* __restrict__ w,
                              float* __restrict__ out) {
    __shared__ float hs[1024];
    __shared__ float part[16][17];
    const int n = blockIdx.x;
    for (int i = threadIdx.x; i < 1024; i += blockDim.x)
        hs[i] = h[(size_t)n * 1024 + i];
    __syncthreads();
    const int j = threadIdx.x & 15, ch = threadIdx.x >> 4;
    float acc = 0.f;
    if (j < 11) {
        const float* wr = w + (size_t)j * 1024 + ch * 64;
        const float* hh = hs + ch * 64;
        #pragma unroll 8
        for (int k = 0; k < 64; ++k) acc = fmaf(hh[k], wr[k], acc);
    }
    part[j][ch] = acc;
    __syncthreads();
    if (threadIdx.x < 11) {
        float s = 0.f;
        #pragma unroll
        for (int cc = 0; cc < 16; ++cc) s += part[threadIdx.x][cc];
        out[(size_t)n * 11 + threadIdx.x] = s;
    }
}

// ---------------------------------------------------------------------------
extern "C" void kernel_launch(void* const* d_in, const int* in_sizes, int n_in,
                              void* d_out, int out_size, void* d_ws, size_t ws_size,
                              hipStream_t stream) {
    const int B = 32, T = 50;

    const float* x   = (const float*)d_in[0];
    const float* c0v = (const float*)d_in[1];
    const float* c0g = (const float*)d_in[2];
    const float* c1v = (const float*)d_in[3];
    const float* c1g = (const float*)d_in[4];
    const float* c2v = (const float*)d_in[5];
    const float* c2g = (const float*)d_in[6];
    const float* c3v = (const float*)d_in[7];
    const float* c3g = (const float*)d_in[8];
    const float* lv  = (const float*)d_in[9];
    const float* lg  = (const float*)d_in[10];
    float* out = (float*)d_out;

    // Workspace layout (floats)
    float* ws = (float*)d_ws;
    float* w0 = ws;                    // 8*2*9     = 144
    float* w1 = w0 + 144;              // 16*8*9    = 1152
    float* w2 = w1 + 1152;             // 32*16*9   = 4608
    float* w3 = w2 + 4608;             // 64*32*9   = 18432
    float* wl = w3 + 18432;            // 11*1024   = 11264
    float* bufA = ws + 40960;                  // L0 out: 1600*8*32*32  = 13,107,200
    float* bufB = bufA + (size_t)13107200;     // L1 out: 1600*16*16*16 =  6,553,600
    // L2 out (3,276,800) reuses bufA; L3 out (1,638,400) reuses bufB.

    wnorm_all<<<131, 64, 0, stream>>>(c0v, c0g, c1v, c1g, c2v, c2g, c3v, c3g,
                                      lv, lg, w0, w1, w2, w3, wl);

    // <CIN,H,COUT,CG,WX,SEGS,BDIM,CIP>  grid = B * STRIPS * CGRP
    conv_iaf_pool<2,  64, 8,  4, 32, 1, 256, 2 ><<<1024, 256, 0, stream>>>(x,    w0, bufA, B, T); // L0
    conv_iaf_pool<8,  32, 16, 4, 32, 1, 256, 12><<<512,  256, 0, stream>>>(bufA, w1, bufB, B, T); // L1
    conv_iaf_pool<16, 16, 32, 2, 16, 2, 256, 20><<<512,  256, 0, stream>>>(bufB, w2, bufA, B, T); // L2
    conv_iaf_pool<32, 8,  64, 2, 8,  2, 128, 36><<<512,  128, 0, stream>>>(bufA, w3, bufB, B, T); // L3

    linear_kernel<<<B * T, 256, 0, stream>>>(bufB, wl, out);
}